// Round 11
// baseline (366.124 us; speedup 1.0000x reference)
//
#include <hip/hip_runtime.h>
#include <hip/hip_bf16.h>
#include <stdint.h>

// ---- All intermediates live inside d_out (16,777,216 f32; 256 slots x 65536 f32).
// Slot q (q=b*64+co): [0,4096) feat plane q ; [4096,8192) cat plane p (p<256, p&255==q)
// [8192,12288) cat plane p (p>=256) ; [12288] mean ; [12289] att ;
// [16384,24576) f64 x1_hi plane q ; [25600,26112) wT chunks (slots 0..143).
__device__ __forceinline__ float* catp(float* o, int p) {
    return o + (size_t)(p & 255) * 65536 + 4096 + ((p >> 8) << 12);
}
__device__ __forceinline__ double* x1hp(float* o, int q) {
    return (double*)(o + (size_t)q * 65536 + 16384);
}
// wT element (kk,co), kk<1152: coalesced across co within one slot chunk.
__device__ __forceinline__ float wtv(const float* o, int kk, int co) {
    return o[(size_t)(kk >> 3) * 65536 + 25600 + (kk & 7) * 64 + co];
}

// ---------------- K0: transpose w1 (64,128,3,3) -> wT[kk][co] in slot-free region
__global__ __launch_bounds__(256) void k0_wtrans(const float* __restrict__ w1, float* __restrict__ o) {
    int idx = blockIdx.x * 256 + threadIdx.x;   // idx = kk*64+co
    if (idx >= 73728) return;
    int co = idx & 63, kk = idx >> 6;
    o[(size_t)(kk >> 3) * 65536 + 25600 + (kk & 7) * 64 + co] = w1[co * 1152 + kk];
}

// ---------------- K1: 4x4/stride-4 conv + BN + ReLU in f64 -> f32 cat ch 0..63 + f64 x1_hi
// grid: 512 = B(4)*I(64)*Jt(2); block 256. LDS 32KB (4 stages of 16 ci). 8 outputs/thread.
__global__ __launch_bounds__(256) void k1_convds(
    const float* __restrict__ x, const float* __restrict__ wd, const float* __restrict__ bd,
    const float* __restrict__ g, const float* __restrict__ be,
    const float* __restrict__ m, const float* __restrict__ v,
    float* __restrict__ o)
{
    __shared__ __align__(16) float tile[16 * 4 * 128];  // [ci16][ky][icol128] 32KB
    int blk = blockIdx.x;
    int jt = blk & 1, i = (blk >> 1) & 63, b = blk >> 7;
    int t = threadIdx.x;
    int co = t & 63, jg = t >> 6;   // 8 outputs j = jt*32 + jg*8 + {0..7}
    double acc0 = 0.0, acc1 = 0.0, acc2 = 0.0, acc3 = 0.0;
    double acc4 = 0.0, acc5 = 0.0, acc6 = 0.0, acc7 = 0.0;
    for (int st = 0; st < 4; ++st) {
        __syncthreads();
        // stage 16ci x 4ky x 128 cols = 2048 float4 chunks (coalesced)
        for (int kk = 0; kk < 8; ++kk) {
            int ch = t + 256 * kk;
            int ci = ch >> 7, y4 = (ch >> 5) & 3, x4 = ch & 31;
            const float* src = x + (((b * 64 + st * 16 + ci) * 256 + (i * 4 + y4)) * 256 + jt * 128 + x4 * 4);
            *(float4*)(tile + (ci * 4 + y4) * 128 + x4 * 4) = *(const float4*)src;
        }
        __syncthreads();
        const float* wco = wd + co * 1024 + st * 256;
        for (int ci = 0; ci < 16; ++ci) {
            #pragma unroll
            for (int ky = 0; ky < 4; ++ky) {
                float4 wv4 = *(const float4*)(wco + ci * 16 + ky * 4);
                double w0 = (double)wv4.x, w1d = (double)wv4.y, w2d = (double)wv4.z, w3d = (double)wv4.w;
                const float* xr = tile + (ci * 4 + ky) * 128 + jg * 32;
                float4 a0 = *(const float4*)(xr);
                float4 a1 = *(const float4*)(xr + 4);
                float4 a2 = *(const float4*)(xr + 8);
                float4 a3 = *(const float4*)(xr + 12);
                float4 a4 = *(const float4*)(xr + 16);
                float4 a5 = *(const float4*)(xr + 20);
                float4 a6 = *(const float4*)(xr + 24);
                float4 a7 = *(const float4*)(xr + 28);
                acc0 = fma(w0, (double)a0.x, fma(w1d, (double)a0.y, fma(w2d, (double)a0.z, fma(w3d, (double)a0.w, acc0))));
                acc1 = fma(w0, (double)a1.x, fma(w1d, (double)a1.y, fma(w2d, (double)a1.z, fma(w3d, (double)a1.w, acc1))));
                acc2 = fma(w0, (double)a2.x, fma(w1d, (double)a2.y, fma(w2d, (double)a2.z, fma(w3d, (double)a2.w, acc2))));
                acc3 = fma(w0, (double)a3.x, fma(w1d, (double)a3.y, fma(w2d, (double)a3.z, fma(w3d, (double)a3.w, acc3))));
                acc4 = fma(w0, (double)a4.x, fma(w1d, (double)a4.y, fma(w2d, (double)a4.z, fma(w3d, (double)a4.w, acc4))));
                acc5 = fma(w0, (double)a5.x, fma(w1d, (double)a5.y, fma(w2d, (double)a5.z, fma(w3d, (double)a5.w, acc5))));
                acc6 = fma(w0, (double)a6.x, fma(w1d, (double)a6.y, fma(w2d, (double)a6.z, fma(w3d, (double)a6.w, acc6))));
                acc7 = fma(w0, (double)a7.x, fma(w1d, (double)a7.y, fma(w2d, (double)a7.z, fma(w3d, (double)a7.w, acc7))));
            }
        }
    }
    double sc = (double)g[co] / sqrt((double)v[co] + 1e-5);
    double sh = (double)bd[co] - (double)m[co];
    double bb = (double)be[co];
    double o0 = fmax(0.0, (acc0 + sh) * sc + bb);
    double o1 = fmax(0.0, (acc1 + sh) * sc + bb);
    double o2 = fmax(0.0, (acc2 + sh) * sc + bb);
    double o3 = fmax(0.0, (acc3 + sh) * sc + bb);
    double o4 = fmax(0.0, (acc4 + sh) * sc + bb);
    double o5 = fmax(0.0, (acc5 + sh) * sc + bb);
    double o6 = fmax(0.0, (acc6 + sh) * sc + bb);
    double o7 = fmax(0.0, (acc7 + sh) * sc + bb);
    int pos = i * 64 + jt * 32 + jg * 8;
    float4 ovA, ovB;
    ovA.x = (float)o0; ovA.y = (float)o1; ovA.z = (float)o2; ovA.w = (float)o3;
    ovB.x = (float)o4; ovB.y = (float)o5; ovB.z = (float)o6; ovB.w = (float)o7;
    float* cp = catp(o, b * 128 + co);
    *(float4*)(cp + pos) = ovA;
    *(float4*)(cp + pos + 4) = ovB;
    double* xh = x1hp(o, b * 64 + co);
    *(double2*)(xh + pos)     = make_double2(o0, o1);
    *(double2*)(xh + pos + 2) = make_double2(o2, o3);
    *(double2*)(xh + pos + 4) = make_double2(o4, o5);
    *(double2*)(xh + pos + 6) = make_double2(o6, o7);
}

// ---------------- K2: windowed d^2 from f64 x1_hi -> top-9 largest d^2 -> f32 neighbor-mean diff
// grid: 256 = B*64 rows; block 256. LDS ~45.6KB (15232B tile aliased f64-phase1/f32-phase4).
__global__ __launch_bounds__(256) void k2_feat(float* __restrict__ o)
{
    __shared__ __align__(16) char smem[15232];
    __shared__ double dotsd[64 * 50];
    __shared__ double sqd[7 * 64];
    __shared__ int sels[64 * 9];
    double* tile_d = (double*)smem;
    float* tileq = (float*)smem;
    int blk = blockIdx.x;
    int b = blk >> 6, i = blk & 63;
    int t = threadIdx.x;
    int lane = t & 63, wv = t >> 6;

    for (int p = t; p < 64 * 50; p += 256) dotsd[p] = 0.0;
    for (int p = t; p < 448; p += 256) sqd[p] = 0.0;

    for (int q = 0; q < 16; ++q) {
        __syncthreads();
        for (int s = t; s < 896; s += 256) {
            int rc = s >> 5, c2 = s & 31;
            int r = rc >> 2, c = rc & 3;
            int gr = i - 3 + r;
            if (gr >= 0 && gr <= 63) {
                const double* src = x1hp(o, b * 64 + q * 4 + c);
                *(double2*)(tile_d + rc * 66 + c2 * 2) = *(const double2*)(src + gr * 64 + c2 * 2);
            }
        }
        __syncthreads();
        for (int p = t; p < 448; p += 256) {
            int r = p >> 6, col = p & 63;
            int gr = i - 3 + r;
            if (gr >= 0 && gr <= 63) {
                double s = 0.0;
                #pragma unroll
                for (int c = 0; c < 4; ++c) {
                    double xv = tile_d[(r * 4 + c) * 66 + col];
                    s = fma(xv, xv, s);
                }
                sqd[p] += s;
            }
        }
        double xlq[4];
        #pragma unroll
        for (int c = 0; c < 4; ++c) xlq[c] = tile_d[(12 + c) * 66 + lane];
        for (int oo = wv; oo < 49; oo += 4) {
            int oi = oo / 7 - 3, oj = oo % 7 - 3;
            int mi = i + oi, mj = lane + oj;
            if (mi >= 0 && mi <= 63 && mj >= 0 && mj <= 63) {
                int r = oi + 3;
                double dot = 0.0;
                #pragma unroll
                for (int c = 0; c < 4; ++c) dot = fma(xlq[c], tile_d[(r * 4 + c) * 66 + mj], dot);
                dotsd[lane * 50 + oo] += dot;
            }
        }
    }
    __syncthreads();
    for (int oo = wv; oo < 49; oo += 4) {
        int oi = oo / 7 - 3, oj = oo % 7 - 3;
        int mi = i + oi, mj = lane + oj;
        double d2 = -1e300;
        if (mi >= 0 && mi <= 63 && mj >= 0 && mj <= 63)
            d2 = sqd[192 + lane] + sqd[(oi + 3) * 64 + mj] - 2.0 * dotsd[lane * 50 + oo];
        dotsd[lane * 50 + oo] = d2;
    }
    __syncthreads();
    if (wv == 0) {
        unsigned long long mask = 0ull;
        for (int k = 0; k < 9; ++k) {
            double best = -1e308; int bi = 0;
            for (int oo = 0; oo < 49; ++oo) {
                if ((mask >> oo) & 1ull) continue;
                double vv = dotsd[lane * 50 + oo];
                if (vv > best) { best = vv; bi = oo; }
            }
            mask |= (1ull << bi);
            sels[lane * 9 + k] = bi;
        }
    }
    __syncthreads();
    int rk[9], cj[9];
    #pragma unroll
    for (int k = 0; k < 9; ++k) {
        int oo = sels[lane * 9 + k];
        rk[k] = oo / 7;
        cj[k] = lane + (oo % 7) - 3;
    }
    for (int q = 0; q < 8; ++q) {
        __syncthreads();
        for (int s = t; s < 896; s += 256) {
            int rc = s >> 4, x4 = s & 15;
            int r = rc >> 3, c = rc & 7;
            int gr = i - 3 + r;
            if (gr >= 0 && gr <= 63)
                *(float4*)(tileq + rc * 68 + x4 * 4) =
                    *(const float4*)(catp(o, b * 128 + q * 8 + c) + gr * 64 + x4 * 4);
        }
        __syncthreads();
        #pragma unroll
        for (int cc = 0; cc < 2; ++cc) {
            int c = wv * 2 + cc;
            float s = 0.f;
            #pragma unroll
            for (int k = 0; k < 9; ++k) s += tileq[(rk[k] * 8 + c) * 68 + cj[k]];
            float outv = s * (1.f / 9.f) - tileq[(24 + c) * 68 + lane];
            catp(o, b * 128 + 64 + q * 8 + c)[i * 64 + lane] = outv;
        }
    }
}

// ---------------- K3: 3x3 conv (128->64) + BN + ReLU -> feat planes (coalesced wT loads)
__global__ __launch_bounds__(256) void k3_conv(
    float* __restrict__ o, const float* __restrict__ b1,
    const float* __restrict__ g, const float* __restrict__ be,
    const float* __restrict__ m, const float* __restrict__ v)
{
    __shared__ __align__(16) float tile[3 * 32 * 72];
    int blk = blockIdx.x;
    int b = blk >> 6, i = blk & 63;
    int t = threadIdx.x;
    int co = t & 63, jg = t >> 6;
    float acc[16];
    #pragma unroll
    for (int jj = 0; jj < 16; ++jj) acc[jj] = 0.f;
    const float4 z4 = make_float4(0.f, 0.f, 0.f, 0.f);
    for (int st = 0; st < 4; ++st) {
        __syncthreads();
        for (int s = t; s < 96; s += 256) {
            float* d = tile + s * 72;
            *(float4*)(d) = z4;
            *(float4*)(d + 68) = z4;
        }
        for (int f = t; f < 1536; f += 256) {
            int x4 = f & 15, ci = (f >> 4) & 31, ry = f >> 9;
            int gr = i - 1 + ry;
            float4 val = z4;
            if (gr >= 0 && gr <= 63)
                val = *(const float4*)(catp(o, b * 128 + st * 32 + ci) + gr * 64 + x4 * 4);
            *(float4*)(tile + (ry * 32 + ci) * 72 + 4 + x4 * 4) = val;
        }
        __syncthreads();
        for (int cl = 0; cl < 32; ++cl) {
            int ci = st * 32 + cl;
            #pragma unroll
            for (int ry = 0; ry < 3; ++ry) {
                int kk = ci * 9 + ry * 3;
                float w0 = wtv(o, kk, co);
                float w1f = wtv(o, kk + 1, co);
                float w2 = wtv(o, kk + 2, co);
                const float* xr = tile + (ry * 32 + cl) * 72 + jg * 16;
                float4 q0 = *(const float4*)(xr);
                float4 q1 = *(const float4*)(xr + 4);
                float4 q2 = *(const float4*)(xr + 8);
                float4 q3 = *(const float4*)(xr + 12);
                float4 q4 = *(const float4*)(xr + 16);
                float4 q5 = *(const float4*)(xr + 20);
                float xv[24] = { q0.x,q0.y,q0.z,q0.w, q1.x,q1.y,q1.z,q1.w,
                                 q2.x,q2.y,q2.z,q2.w, q3.x,q3.y,q3.z,q3.w,
                                 q4.x,q4.y,q4.z,q4.w, q5.x,q5.y,q5.z,q5.w };
                #pragma unroll
                for (int jj = 0; jj < 16; ++jj)
                    acc[jj] = fmaf(w0, xv[jj + 3], fmaf(w1f, xv[jj + 4], fmaf(w2, xv[jj + 5], acc[jj])));
            }
        }
    }
    float sc = g[co] * rsqrtf(v[co] + 1e-5f);
    float sh = b1[co] - m[co];
    float bb = be[co];
    float* fp = o + (size_t)(b * 64 + co) * 65536 + i * 64 + jg * 16;
    #pragma unroll
    for (int q = 0; q < 4; ++q) {
        float4 ov;
        ov.x = fmaxf(0.f, fmaf(acc[q * 4 + 0] + sh, sc, bb));
        ov.y = fmaxf(0.f, fmaf(acc[q * 4 + 1] + sh, sc, bb));
        ov.z = fmaxf(0.f, fmaf(acc[q * 4 + 2] + sh, sc, bb));
        ov.w = fmaxf(0.f, fmaf(acc[q * 4 + 3] + sh, sc, bb));
        *(float4*)(fp + q * 4) = ov;
    }
}

// ---------------- K4a: per-plane spatial mean -> slot[12288]
__global__ __launch_bounds__(256) void k4_mean(float* __restrict__ o) {
    int q = blockIdx.x, t = threadIdx.x;
    const float* p = o + (size_t)q * 65536;
    float s = 0.f;
    for (int k = t; k < 4096; k += 256) s += p[k];
    #pragma unroll
    for (int off = 32; off > 0; off >>= 1) s += __shfl_down(s, off, 64);
    __shared__ float red[4];
    if ((t & 63) == 0) red[t >> 6] = s;
    __syncthreads();
    if (t == 0) o[(size_t)q * 65536 + 12288] = (red[0] + red[1] + red[2] + red[3]) * (1.f / 4096.f);
}

// ---------------- K4b: 1x1 conv + BN + sigmoid -> slot[12289]
__global__ __launch_bounds__(256) void k4_att(float* __restrict__ o, const float* __restrict__ wa,
    const float* __restrict__ g, const float* __restrict__ be, const float* __restrict__ m, const float* __restrict__ v) {
    int t = threadIdx.x;
    int b = t >> 6, co = t & 63;
    const float* wr = wa + co * 64;
    float s = 0.f;
    for (int ci = 0; ci < 64; ++ci) s = fmaf(wr[ci], o[(size_t)(b * 64 + ci) * 65536 + 12288], s);
    float sc = g[co] * rsqrtf(v[co] + 1e-5f);
    float y = fmaf(s - m[co], sc, be[co]);
    o[(size_t)t * 65536 + 12289] = 1.f / (1.f + expf(-y));
}

// ---------------- K5: out = bilinear_x4(feat)*att, f32 in place over own slot (race-free).
__global__ __launch_bounds__(256) void k5_up(float* __restrict__ o) {
    __shared__ __align__(16) float fplane[4096];
    int bc = blockIdx.x;
    int t = threadIdx.x;
    float* slot = o + (size_t)bc * 65536;
    #pragma unroll
    for (int kk = 0; kk < 4; ++kk) {
        int idx = t + 256 * kk;
        *(float4*)(fplane + idx * 4) = *(const float4*)(slot + idx * 4);
    }
    float att = slot[12289];
    __syncthreads();
    int ox = t;
    float fx = ox * 0.25f - 0.375f;
    int ix = (int)floorf(fx);
    float wx = fx - (float)ix;
    int x0 = ix < 0 ? 0 : ix;
    int x1 = (ix + 1 > 63) ? 63 : ix + 1;
    for (int oy = 0; oy < 256; ++oy) {
        float fy = oy * 0.25f - 0.375f;
        int iy = (int)floorf(fy);
        float wy = fy - (float)iy;
        int y0 = iy < 0 ? 0 : iy;
        int y1 = (iy + 1 > 63) ? 63 : iy + 1;
        float a  = fplane[y0 * 64 + x0], b_ = fplane[y0 * 64 + x1];
        float c_ = fplane[y1 * 64 + x0], d_ = fplane[y1 * 64 + x1];
        float top = a + wx * (b_ - a);
        float bot = c_ + wx * (d_ - c_);
        float val = (top + wy * (bot - top)) * att;
        slot[oy * 256 + ox] = val;
    }
}

extern "C" void kernel_launch(void* const* d_in, const int* in_sizes, int n_in,
                              void* d_out, int out_size, void* d_ws, size_t ws_size,
                              hipStream_t stream) {
    const float* x     = (const float*)d_in[0];
    const float* wd    = (const float*)d_in[1];
    const float* bd    = (const float*)d_in[2];
    const float* bnd_g = (const float*)d_in[3];
    const float* bnd_b = (const float*)d_in[4];
    const float* bnd_m = (const float*)d_in[5];
    const float* bnd_v = (const float*)d_in[6];
    const float* w1    = (const float*)d_in[7];
    const float* b1    = (const float*)d_in[8];
    const float* bn1_g = (const float*)d_in[9];
    const float* bn1_b = (const float*)d_in[10];
    const float* bn1_m = (const float*)d_in[11];
    const float* bn1_v = (const float*)d_in[12];
    const float* wa    = (const float*)d_in[13];
    const float* bna_g = (const float*)d_in[14];
    const float* bna_b = (const float*)d_in[15];
    const float* bna_m = (const float*)d_in[16];
    const float* bna_v = (const float*)d_in[17];

    float* o = (float*)d_out;   // f32 output; all scratch lives inside d_out; d_ws unused

    hipLaunchKernelGGL(k0_wtrans, dim3(288), dim3(256), 0, stream, w1, o);
    hipLaunchKernelGGL(k1_convds, dim3(512), dim3(256), 0, stream,
                       x, wd, bd, bnd_g, bnd_b, bnd_m, bnd_v, o);
    hipLaunchKernelGGL(k2_feat, dim3(256), dim3(256), 0, stream, o);
    hipLaunchKernelGGL(k3_conv, dim3(256), dim3(256), 0, stream,
                       o, b1, bn1_g, bn1_b, bn1_m, bn1_v);
    hipLaunchKernelGGL(k4_mean, dim3(256), dim3(256), 0, stream, o);
    hipLaunchKernelGGL(k4_att, dim3(1), dim3(256), 0, stream,
                       o, wa, bna_g, bna_b, bna_m, bna_v);
    hipLaunchKernelGGL(k5_up, dim3(256), dim3(256), 0, stream, o);
}

// Round 12
// 319.090 us; speedup vs baseline: 1.1474x; 1.1474x over previous
//
#include <hip/hip_runtime.h>
#include <hip/hip_bf16.h>
#include <stdint.h>

// ---- All intermediates live inside d_out (16,777,216 f32; 256 slots x 65536 f32).
// Slot q (q=b*64+co): [0,4096) feat plane q ; [4096,8192) cat plane p (p<256, p&255==q)
// [8192,12288) cat plane p (p>=256) ; [12288] mean ; [12289] att ;
// [16384,24576) f64 x1_hi plane q ; [25600,26112) wT chunks (slots 0..143).
__device__ __forceinline__ float* catp(float* o, int p) {
    return o + (size_t)(p & 255) * 65536 + 4096 + ((p >> 8) << 12);
}
__device__ __forceinline__ double* x1hp(float* o, int q) {
    return (double*)(o + (size_t)q * 65536 + 16384);
}
__device__ __forceinline__ float wtv(const float* o, int kk, int co) {
    return o[(size_t)(kk >> 3) * 65536 + 25600 + (kk & 7) * 64 + co];
}

// ---------------- K0: transpose w1 (64,128,3,3) -> wT[kk][co] in slot-free region
__global__ __launch_bounds__(256) void k0_wtrans(const float* __restrict__ w1, float* __restrict__ o) {
    int idx = blockIdx.x * 256 + threadIdx.x;
    if (idx >= 73728) return;
    int co = idx & 63, kk = idx >> 6;
    o[(size_t)(kk >> 3) * 65536 + 25600 + (kk & 7) * 64 + co] = w1[co * 1152 + kk];
}

// ---------------- K1: 4x4/stride-4 conv + BN + ReLU in f64 -> f32 cat ch 0..63 + f64 x1_hi
// grid: 512 = B(4)*I(64)*Jt(2); block 256. LDS 32KB. 8 outputs/thread.
__global__ __launch_bounds__(256) void k1_convds(
    const float* __restrict__ x, const float* __restrict__ wd, const float* __restrict__ bd,
    const float* __restrict__ g, const float* __restrict__ be,
    const float* __restrict__ m, const float* __restrict__ v,
    float* __restrict__ o)
{
    __shared__ __align__(16) float tile[16 * 4 * 128];
    int blk = blockIdx.x;
    int jt = blk & 1, i = (blk >> 1) & 63, b = blk >> 7;
    int t = threadIdx.x;
    int co = t & 63, jg = t >> 6;
    double acc0 = 0.0, acc1 = 0.0, acc2 = 0.0, acc3 = 0.0;
    double acc4 = 0.0, acc5 = 0.0, acc6 = 0.0, acc7 = 0.0;
    for (int st = 0; st < 4; ++st) {
        __syncthreads();
        for (int kk = 0; kk < 8; ++kk) {
            int ch = t + 256 * kk;
            int ci = ch >> 7, y4 = (ch >> 5) & 3, x4 = ch & 31;
            const float* src = x + (((b * 64 + st * 16 + ci) * 256 + (i * 4 + y4)) * 256 + jt * 128 + x4 * 4);
            *(float4*)(tile + (ci * 4 + y4) * 128 + x4 * 4) = *(const float4*)src;
        }
        __syncthreads();
        const float* wco = wd + co * 1024 + st * 256;
        for (int ci = 0; ci < 16; ++ci) {
            #pragma unroll
            for (int ky = 0; ky < 4; ++ky) {
                float4 wv4 = *(const float4*)(wco + ci * 16 + ky * 4);
                double w0 = (double)wv4.x, w1d = (double)wv4.y, w2d = (double)wv4.z, w3d = (double)wv4.w;
                const float* xr = tile + (ci * 4 + ky) * 128 + jg * 32;
                float4 a0 = *(const float4*)(xr);
                float4 a1 = *(const float4*)(xr + 4);
                float4 a2 = *(const float4*)(xr + 8);
                float4 a3 = *(const float4*)(xr + 12);
                float4 a4 = *(const float4*)(xr + 16);
                float4 a5 = *(const float4*)(xr + 20);
                float4 a6 = *(const float4*)(xr + 24);
                float4 a7 = *(const float4*)(xr + 28);
                acc0 = fma(w0, (double)a0.x, fma(w1d, (double)a0.y, fma(w2d, (double)a0.z, fma(w3d, (double)a0.w, acc0))));
                acc1 = fma(w0, (double)a1.x, fma(w1d, (double)a1.y, fma(w2d, (double)a1.z, fma(w3d, (double)a1.w, acc1))));
                acc2 = fma(w0, (double)a2.x, fma(w1d, (double)a2.y, fma(w2d, (double)a2.z, fma(w3d, (double)a2.w, acc2))));
                acc3 = fma(w0, (double)a3.x, fma(w1d, (double)a3.y, fma(w2d, (double)a3.z, fma(w3d, (double)a3.w, acc3))));
                acc4 = fma(w0, (double)a4.x, fma(w1d, (double)a4.y, fma(w2d, (double)a4.z, fma(w3d, (double)a4.w, acc4))));
                acc5 = fma(w0, (double)a5.x, fma(w1d, (double)a5.y, fma(w2d, (double)a5.z, fma(w3d, (double)a5.w, acc5))));
                acc6 = fma(w0, (double)a6.x, fma(w1d, (double)a6.y, fma(w2d, (double)a6.z, fma(w3d, (double)a6.w, acc6))));
                acc7 = fma(w0, (double)a7.x, fma(w1d, (double)a7.y, fma(w2d, (double)a7.z, fma(w3d, (double)a7.w, acc7))));
            }
        }
    }
    double sc = (double)g[co] / sqrt((double)v[co] + 1e-5);
    double sh = (double)bd[co] - (double)m[co];
    double bb = (double)be[co];
    double o0 = fmax(0.0, (acc0 + sh) * sc + bb);
    double o1 = fmax(0.0, (acc1 + sh) * sc + bb);
    double o2 = fmax(0.0, (acc2 + sh) * sc + bb);
    double o3 = fmax(0.0, (acc3 + sh) * sc + bb);
    double o4 = fmax(0.0, (acc4 + sh) * sc + bb);
    double o5 = fmax(0.0, (acc5 + sh) * sc + bb);
    double o6 = fmax(0.0, (acc6 + sh) * sc + bb);
    double o7 = fmax(0.0, (acc7 + sh) * sc + bb);
    int pos = i * 64 + jt * 32 + jg * 8;
    float4 ovA, ovB;
    ovA.x = (float)o0; ovA.y = (float)o1; ovA.z = (float)o2; ovA.w = (float)o3;
    ovB.x = (float)o4; ovB.y = (float)o5; ovB.z = (float)o6; ovB.w = (float)o7;
    float* cp = catp(o, b * 128 + co);
    *(float4*)(cp + pos) = ovA;
    *(float4*)(cp + pos + 4) = ovB;
    double* xh = x1hp(o, b * 64 + co);
    *(double2*)(xh + pos)     = make_double2(o0, o1);
    *(double2*)(xh + pos + 2) = make_double2(o2, o3);
    *(double2*)(xh + pos + 4) = make_double2(o4, o5);
    *(double2*)(xh + pos + 6) = make_double2(o6, o7);
}

// ---------------- K2: windowed d^2 (f64) -> top-9 -> f32 neighbor-mean diff. block 512.
__global__ __launch_bounds__(512) void k2_feat(float* __restrict__ o)
{
    __shared__ __align__(16) char smem[15232];
    __shared__ double dotsd[64 * 50];
    __shared__ double sqd[7 * 64];
    __shared__ int sels[64 * 9];
    double* tile_d = (double*)smem;
    float* tileq = (float*)smem;
    int blk = blockIdx.x;
    int b = blk >> 6, i = blk & 63;
    int t = threadIdx.x;
    int lane = t & 63, wv = t >> 6;   // wv 0..7

    for (int p = t; p < 64 * 50; p += 512) dotsd[p] = 0.0;
    for (int p = t; p < 448; p += 512) sqd[p] = 0.0;

    for (int q = 0; q < 16; ++q) {
        __syncthreads();
        for (int s = t; s < 896; s += 512) {
            int rc = s >> 5, c2 = s & 31;
            int r = rc >> 2, c = rc & 3;
            int gr = i - 3 + r;
            if (gr >= 0 && gr <= 63) {
                const double* src = x1hp(o, b * 64 + q * 4 + c);
                *(double2*)(tile_d + rc * 66 + c2 * 2) = *(const double2*)(src + gr * 64 + c2 * 2);
            }
        }
        __syncthreads();
        for (int p = t; p < 448; p += 512) {
            int r = p >> 6, col = p & 63;
            int gr = i - 3 + r;
            if (gr >= 0 && gr <= 63) {
                double s = 0.0;
                #pragma unroll
                for (int c = 0; c < 4; ++c) {
                    double xv = tile_d[(r * 4 + c) * 66 + col];
                    s = fma(xv, xv, s);
                }
                sqd[p] += s;
            }
        }
        double xlq[4];
        #pragma unroll
        for (int c = 0; c < 4; ++c) xlq[c] = tile_d[(12 + c) * 66 + lane];
        for (int oo = wv; oo < 49; oo += 8) {
            int oi = oo / 7 - 3, oj = oo % 7 - 3;
            int mi = i + oi, mj = lane + oj;
            if (mi >= 0 && mi <= 63 && mj >= 0 && mj <= 63) {
                int r = oi + 3;
                double dot = 0.0;
                #pragma unroll
                for (int c = 0; c < 4; ++c) dot = fma(xlq[c], tile_d[(r * 4 + c) * 66 + mj], dot);
                dotsd[lane * 50 + oo] += dot;
            }
        }
    }
    __syncthreads();
    for (int oo = wv; oo < 49; oo += 8) {
        int oi = oo / 7 - 3, oj = oo % 7 - 3;
        int mi = i + oi, mj = lane + oj;
        double d2 = -1e300;
        if (mi >= 0 && mi <= 63 && mj >= 0 && mj <= 63)
            d2 = sqd[192 + lane] + sqd[(oi + 3) * 64 + mj] - 2.0 * dotsd[lane * 50 + oo];
        dotsd[lane * 50 + oo] = d2;
    }
    __syncthreads();
    if (wv == 0) {
        unsigned long long mask = 0ull;
        for (int k = 0; k < 9; ++k) {
            double best = -1e308; int bi = 0;
            for (int oo = 0; oo < 49; ++oo) {
                if ((mask >> oo) & 1ull) continue;
                double vv = dotsd[lane * 50 + oo];
                if (vv > best) { best = vv; bi = oo; }
            }
            mask |= (1ull << bi);
            sels[lane * 9 + k] = bi;
        }
    }
    __syncthreads();
    int rk[9], cj[9];
    #pragma unroll
    for (int k = 0; k < 9; ++k) {
        int oo = sels[lane * 9 + k];
        rk[k] = oo / 7;
        cj[k] = lane + (oo % 7) - 3;
    }
    for (int q = 0; q < 8; ++q) {
        __syncthreads();
        for (int s = t; s < 896; s += 512) {
            int rc = s >> 4, x4 = s & 15;
            int r = rc >> 3, c = rc & 7;
            int gr = i - 3 + r;
            if (gr >= 0 && gr <= 63)
                *(float4*)(tileq + rc * 68 + x4 * 4) =
                    *(const float4*)(catp(o, b * 128 + q * 8 + c) + gr * 64 + x4 * 4);
        }
        __syncthreads();
        {
            int c = wv;   // 8 groups, one channel each
            float s = 0.f;
            #pragma unroll
            for (int k = 0; k < 9; ++k) s += tileq[(rk[k] * 8 + c) * 68 + cj[k]];
            float outv = s * (1.f / 9.f) - tileq[(24 + c) * 68 + lane];
            catp(o, b * 128 + 64 + q * 8 + c)[i * 64 + lane] = outv;
        }
    }
}

// ---------------- K3: 3x3 conv (128->64) + BN + ReLU -> feat planes
// grid: 1024 = B(4)*I(64)*Jt(4); block 256; 16 cols/block; LDS 9.2KB -> 4 blocks/CU.
__global__ __launch_bounds__(256) void k3_conv(
    float* __restrict__ o, const float* __restrict__ b1,
    const float* __restrict__ g, const float* __restrict__ be,
    const float* __restrict__ m, const float* __restrict__ v)
{
    __shared__ __align__(16) float tile[3 * 32 * 24];   // [ry][ci][cidx24], data col = jt*16-4+cidx
    int blk = blockIdx.x;
    int jt = blk & 3, i = (blk >> 2) & 63, b = blk >> 8;
    int t = threadIdx.x;
    int co = t & 63, jg = t >> 6;
    float acc0 = 0.f, acc1 = 0.f, acc2 = 0.f, acc3 = 0.f;
    const float4 z4 = make_float4(0.f, 0.f, 0.f, 0.f);
    for (int st = 0; st < 4; ++st) {
        __syncthreads();
        // stage 3ry x 32ci x 6 float4 chunks = 576
        for (int f = t; f < 576; f += 256) {
            int x4 = f % 6, rc = f / 6;
            int ci = rc & 31, ry = rc >> 5;
            int gr = i - 1 + ry;
            int col0 = jt * 16 - 4 + x4 * 4;
            float4 val = z4;
            if (gr >= 0 && gr <= 63 && col0 >= 0 && col0 <= 60)
                val = *(const float4*)(catp(o, b * 128 + st * 32 + ci) + gr * 64 + col0);
            *(float4*)(tile + (ry * 32 + ci) * 24 + x4 * 4) = val;
        }
        __syncthreads();
        for (int cl = 0; cl < 32; ++cl) {
            int ci = st * 32 + cl;
            #pragma unroll
            for (int ry = 0; ry < 3; ++ry) {
                int kk = ci * 9 + ry * 3;
                float w0 = wtv(o, kk, co);
                float w1f = wtv(o, kk + 1, co);
                float w2 = wtv(o, kk + 2, co);
                const float* xr = tile + (ry * 32 + cl) * 24 + jg * 4;
                float4 q0 = *(const float4*)(xr);
                float4 q1 = *(const float4*)(xr + 4);
                float4 q2 = *(const float4*)(xr + 8);
                float xv[12] = { q0.x,q0.y,q0.z,q0.w, q1.x,q1.y,q1.z,q1.w, q2.x,q2.y,q2.z,q2.w };
                acc0 = fmaf(w0, xv[3], fmaf(w1f, xv[4], fmaf(w2, xv[5], acc0)));
                acc1 = fmaf(w0, xv[4], fmaf(w1f, xv[5], fmaf(w2, xv[6], acc1)));
                acc2 = fmaf(w0, xv[5], fmaf(w1f, xv[6], fmaf(w2, xv[7], acc2)));
                acc3 = fmaf(w0, xv[6], fmaf(w1f, xv[7], fmaf(w2, xv[8], acc3)));
            }
        }
    }
    float sc = g[co] * rsqrtf(v[co] + 1e-5f);
    float sh = b1[co] - m[co];
    float bb = be[co];
    float4 ov;
    ov.x = fmaxf(0.f, fmaf(acc0 + sh, sc, bb));
    ov.y = fmaxf(0.f, fmaf(acc1 + sh, sc, bb));
    ov.z = fmaxf(0.f, fmaf(acc2 + sh, sc, bb));
    ov.w = fmaxf(0.f, fmaf(acc3 + sh, sc, bb));
    *(float4*)(o + (size_t)(b * 64 + co) * 65536 + i * 64 + jt * 16 + jg * 4) = ov;
}

// ---------------- K4a: per-plane spatial mean -> slot[12288]
__global__ __launch_bounds__(256) void k4_mean(float* __restrict__ o) {
    int q = blockIdx.x, t = threadIdx.x;
    const float* p = o + (size_t)q * 65536;
    float s = 0.f;
    for (int k = t; k < 4096; k += 256) s += p[k];
    #pragma unroll
    for (int off = 32; off > 0; off >>= 1) s += __shfl_down(s, off, 64);
    __shared__ float red[4];
    if ((t & 63) == 0) red[t >> 6] = s;
    __syncthreads();
    if (t == 0) o[(size_t)q * 65536 + 12288] = (red[0] + red[1] + red[2] + red[3]) * (1.f / 4096.f);
}

// ---------------- K4b: 1x1 conv + BN + sigmoid -> slot[12289]
__global__ __launch_bounds__(256) void k4_att(float* __restrict__ o, const float* __restrict__ wa,
    const float* __restrict__ g, const float* __restrict__ be, const float* __restrict__ m, const float* __restrict__ v) {
    int t = threadIdx.x;
    int b = t >> 6, co = t & 63;
    const float* wr = wa + co * 64;
    float s = 0.f;
    for (int ci = 0; ci < 64; ++ci) s = fmaf(wr[ci], o[(size_t)(b * 64 + ci) * 65536 + 12288], s);
    float sc = g[co] * rsqrtf(v[co] + 1e-5f);
    float y = fmaf(s - m[co], sc, be[co]);
    o[(size_t)t * 65536 + 12289] = 1.f / (1.f + expf(-y));
}

// ---------------- K5: out = bilinear_x4(feat)*att, in place over own slot. block 1024.
__global__ __launch_bounds__(1024) void k5_up(float* __restrict__ o) {
    __shared__ __align__(16) float fplane[4096];
    int bc = blockIdx.x;
    int t = threadIdx.x;
    float* slot = o + (size_t)bc * 65536;
    *(float4*)(fplane + t * 4) = *(const float4*)(slot + t * 4);
    float att = slot[12289];
    __syncthreads();
    int ox = t & 255, oyc = t >> 8;
    float fx = ox * 0.25f - 0.375f;
    int ix = (int)floorf(fx);
    float wx = fx - (float)ix;
    int x0 = ix < 0 ? 0 : ix;
    int x1 = (ix + 1 > 63) ? 63 : ix + 1;
    for (int oy = oyc * 64; oy < oyc * 64 + 64; ++oy) {
        float fy = oy * 0.25f - 0.375f;
        int iy = (int)floorf(fy);
        float wy = fy - (float)iy;
        int y0 = iy < 0 ? 0 : iy;
        int y1 = (iy + 1 > 63) ? 63 : iy + 1;
        float a  = fplane[y0 * 64 + x0], b_ = fplane[y0 * 64 + x1];
        float c_ = fplane[y1 * 64 + x0], d_ = fplane[y1 * 64 + x1];
        float top = a + wx * (b_ - a);
        float bot = c_ + wx * (d_ - c_);
        float val = (top + wy * (bot - top)) * att;
        slot[oy * 256 + ox] = val;
    }
}

extern "C" void kernel_launch(void* const* d_in, const int* in_sizes, int n_in,
                              void* d_out, int out_size, void* d_ws, size_t ws_size,
                              hipStream_t stream) {
    const float* x     = (const float*)d_in[0];
    const float* wd    = (const float*)d_in[1];
    const float* bd    = (const float*)d_in[2];
    const float* bnd_g = (const float*)d_in[3];
    const float* bnd_b = (const float*)d_in[4];
    const float* bnd_m = (const float*)d_in[5];
    const float* bnd_v = (const float*)d_in[6];
    const float* w1    = (const float*)d_in[7];
    const float* b1    = (const float*)d_in[8];
    const float* bn1_g = (const float*)d_in[9];
    const float* bn1_b = (const float*)d_in[10];
    const float* bn1_m = (const float*)d_in[11];
    const float* bn1_v = (const float*)d_in[12];
    const float* wa    = (const float*)d_in[13];
    const float* bna_g = (const float*)d_in[14];
    const float* bna_b = (const float*)d_in[15];
    const float* bna_m = (const float*)d_in[16];
    const float* bna_v = (const float*)d_in[17];

    float* o = (float*)d_out;

    hipLaunchKernelGGL(k0_wtrans, dim3(288), dim3(256), 0, stream, w1, o);
    hipLaunchKernelGGL(k1_convds, dim3(512), dim3(256), 0, stream,
                       x, wd, bd, bnd_g, bnd_b, bnd_m, bnd_v, o);
    hipLaunchKernelGGL(k2_feat, dim3(256), dim3(512), 0, stream, o);
    hipLaunchKernelGGL(k3_conv, dim3(1024), dim3(256), 0, stream,
                       o, b1, bn1_g, bn1_b, bn1_m, bn1_v);
    hipLaunchKernelGGL(k4_mean, dim3(256), dim3(256), 0, stream, o);
    hipLaunchKernelGGL(k4_att, dim3(1), dim3(256), 0, stream,
                       o, wa, bna_g, bna_b, bna_m, bna_v);
    hipLaunchKernelGGL(k5_up, dim3(256), dim3(1024), 0, stream, o);
}

// Round 13
// 273.045 us; speedup vs baseline: 1.3409x; 1.1686x over previous
//
#include <hip/hip_runtime.h>
#include <hip/hip_bf16.h>
#include <stdint.h>

// ---- All intermediates live inside d_out (16,777,216 f32; 256 slots x 65536 f32).
// Slot q (q=b*64+co): [0,4096) feat plane q ; [4096,8192) cat plane p (p<256, p&255==q)
// [8192,12288) cat plane p (p>=256) ; [12288] mean ; [12289] att ;
// [16384,24576) f64 x1_hi plane q ; [25600,26112) wT chunks (slots 0..143).
__device__ __forceinline__ float* catp(float* o, int p) {
    return o + (size_t)(p & 255) * 65536 + 4096 + ((p >> 8) << 12);
}
__device__ __forceinline__ double* x1hp(float* o, int q) {
    return (double*)(o + (size_t)q * 65536 + 16384);
}
__device__ __forceinline__ float wtv(const float* o, int kk, int co) {
    return o[(size_t)(kk >> 3) * 65536 + 25600 + (kk & 7) * 64 + co];
}

// ---------------- K0: transpose w1 (64,128,3,3) -> wT[kk][co] in slot-free region
__global__ __launch_bounds__(256) void k0_wtrans(const float* __restrict__ w1, float* __restrict__ o) {
    int idx = blockIdx.x * 256 + threadIdx.x;
    if (idx >= 73728) return;
    int co = idx & 63, kk = idx >> 6;
    o[(size_t)(kk >> 3) * 65536 + 25600 + (kk & 7) * 64 + co] = w1[co * 1152 + kk];
}

// ---------------- K1: 4x4/stride-4 conv + BN + ReLU in f64 -> f32 cat ch 0..63 + f64 x1_hi
// grid: 512 = B(4)*I(64)*Jt(2); block 256. LDS 32KB. 8 outputs/thread.
__global__ __launch_bounds__(256) void k1_convds(
    const float* __restrict__ x, const float* __restrict__ wd, const float* __restrict__ bd,
    const float* __restrict__ g, const float* __restrict__ be,
    const float* __restrict__ m, const float* __restrict__ v,
    float* __restrict__ o)
{
    __shared__ __align__(16) float tile[16 * 4 * 128];
    int blk = blockIdx.x;
    int jt = blk & 1, i = (blk >> 1) & 63, b = blk >> 7;
    int t = threadIdx.x;
    int co = t & 63, jg = t >> 6;
    double acc0 = 0.0, acc1 = 0.0, acc2 = 0.0, acc3 = 0.0;
    double acc4 = 0.0, acc5 = 0.0, acc6 = 0.0, acc7 = 0.0;
    for (int st = 0; st < 4; ++st) {
        __syncthreads();
        for (int kk = 0; kk < 8; ++kk) {
            int ch = t + 256 * kk;
            int ci = ch >> 7, y4 = (ch >> 5) & 3, x4 = ch & 31;
            const float* src = x + (((b * 64 + st * 16 + ci) * 256 + (i * 4 + y4)) * 256 + jt * 128 + x4 * 4);
            *(float4*)(tile + (ci * 4 + y4) * 128 + x4 * 4) = *(const float4*)src;
        }
        __syncthreads();
        const float* wco = wd + co * 1024 + st * 256;
        for (int ci = 0; ci < 16; ++ci) {
            #pragma unroll
            for (int ky = 0; ky < 4; ++ky) {
                float4 wv4 = *(const float4*)(wco + ci * 16 + ky * 4);
                double w0 = (double)wv4.x, w1d = (double)wv4.y, w2d = (double)wv4.z, w3d = (double)wv4.w;
                const float* xr = tile + (ci * 4 + ky) * 128 + jg * 32;
                float4 a0 = *(const float4*)(xr);
                float4 a1 = *(const float4*)(xr + 4);
                float4 a2 = *(const float4*)(xr + 8);
                float4 a3 = *(const float4*)(xr + 12);
                float4 a4 = *(const float4*)(xr + 16);
                float4 a5 = *(const float4*)(xr + 20);
                float4 a6 = *(const float4*)(xr + 24);
                float4 a7 = *(const float4*)(xr + 28);
                acc0 = fma(w0, (double)a0.x, fma(w1d, (double)a0.y, fma(w2d, (double)a0.z, fma(w3d, (double)a0.w, acc0))));
                acc1 = fma(w0, (double)a1.x, fma(w1d, (double)a1.y, fma(w2d, (double)a1.z, fma(w3d, (double)a1.w, acc1))));
                acc2 = fma(w0, (double)a2.x, fma(w1d, (double)a2.y, fma(w2d, (double)a2.z, fma(w3d, (double)a2.w, acc2))));
                acc3 = fma(w0, (double)a3.x, fma(w1d, (double)a3.y, fma(w2d, (double)a3.z, fma(w3d, (double)a3.w, acc3))));
                acc4 = fma(w0, (double)a4.x, fma(w1d, (double)a4.y, fma(w2d, (double)a4.z, fma(w3d, (double)a4.w, acc4))));
                acc5 = fma(w0, (double)a5.x, fma(w1d, (double)a5.y, fma(w2d, (double)a5.z, fma(w3d, (double)a5.w, acc5))));
                acc6 = fma(w0, (double)a6.x, fma(w1d, (double)a6.y, fma(w2d, (double)a6.z, fma(w3d, (double)a6.w, acc6))));
                acc7 = fma(w0, (double)a7.x, fma(w1d, (double)a7.y, fma(w2d, (double)a7.z, fma(w3d, (double)a7.w, acc7))));
            }
        }
    }
    double sc = (double)g[co] / sqrt((double)v[co] + 1e-5);
    double sh = (double)bd[co] - (double)m[co];
    double bb = (double)be[co];
    double o0 = fmax(0.0, (acc0 + sh) * sc + bb);
    double o1 = fmax(0.0, (acc1 + sh) * sc + bb);
    double o2 = fmax(0.0, (acc2 + sh) * sc + bb);
    double o3 = fmax(0.0, (acc3 + sh) * sc + bb);
    double o4 = fmax(0.0, (acc4 + sh) * sc + bb);
    double o5 = fmax(0.0, (acc5 + sh) * sc + bb);
    double o6 = fmax(0.0, (acc6 + sh) * sc + bb);
    double o7 = fmax(0.0, (acc7 + sh) * sc + bb);
    int pos = i * 64 + jt * 32 + jg * 8;
    float4 ovA, ovB;
    ovA.x = (float)o0; ovA.y = (float)o1; ovA.z = (float)o2; ovA.w = (float)o3;
    ovB.x = (float)o4; ovB.y = (float)o5; ovB.z = (float)o6; ovB.w = (float)o7;
    float* cp = catp(o, b * 128 + co);
    *(float4*)(cp + pos) = ovA;
    *(float4*)(cp + pos + 4) = ovB;
    double* xh = x1hp(o, b * 64 + co);
    *(double2*)(xh + pos)     = make_double2(o0, o1);
    *(double2*)(xh + pos + 2) = make_double2(o2, o3);
    *(double2*)(xh + pos + 4) = make_double2(o4, o5);
    *(double2*)(xh + pos + 6) = make_double2(o6, o7);
}

// ---------------- K2: windowed d^2 (f64) -> top-9 -> f32 neighbor-mean diff. block 512.
__global__ __launch_bounds__(512) void k2_feat(float* __restrict__ o)
{
    __shared__ __align__(16) char smem[15232];
    __shared__ double dotsd[64 * 50];
    __shared__ double sqd[7 * 64];
    __shared__ int sels[64 * 9];
    double* tile_d = (double*)smem;
    float* tileq = (float*)smem;
    int blk = blockIdx.x;
    int b = blk >> 6, i = blk & 63;
    int t = threadIdx.x;
    int lane = t & 63, wv = t >> 6;

    for (int p = t; p < 64 * 50; p += 512) dotsd[p] = 0.0;
    for (int p = t; p < 448; p += 512) sqd[p] = 0.0;

    for (int q = 0; q < 16; ++q) {
        __syncthreads();
        for (int s = t; s < 896; s += 512) {
            int rc = s >> 5, c2 = s & 31;
            int r = rc >> 2, c = rc & 3;
            int gr = i - 3 + r;
            if (gr >= 0 && gr <= 63) {
                const double* src = x1hp(o, b * 64 + q * 4 + c);
                *(double2*)(tile_d + rc * 66 + c2 * 2) = *(const double2*)(src + gr * 64 + c2 * 2);
            }
        }
        __syncthreads();
        for (int p = t; p < 448; p += 512) {
            int r = p >> 6, col = p & 63;
            int gr = i - 3 + r;
            if (gr >= 0 && gr <= 63) {
                double s = 0.0;
                #pragma unroll
                for (int c = 0; c < 4; ++c) {
                    double xv = tile_d[(r * 4 + c) * 66 + col];
                    s = fma(xv, xv, s);
                }
                sqd[p] += s;
            }
        }
        double xlq[4];
        #pragma unroll
        for (int c = 0; c < 4; ++c) xlq[c] = tile_d[(12 + c) * 66 + lane];
        for (int oo = wv; oo < 49; oo += 8) {
            int oi = oo / 7 - 3, oj = oo % 7 - 3;
            int mi = i + oi, mj = lane + oj;
            if (mi >= 0 && mi <= 63 && mj >= 0 && mj <= 63) {
                int r = oi + 3;
                double dot = 0.0;
                #pragma unroll
                for (int c = 0; c < 4; ++c) dot = fma(xlq[c], tile_d[(r * 4 + c) * 66 + mj], dot);
                dotsd[lane * 50 + oo] += dot;
            }
        }
    }
    __syncthreads();
    for (int oo = wv; oo < 49; oo += 8) {
        int oi = oo / 7 - 3, oj = oo % 7 - 3;
        int mi = i + oi, mj = lane + oj;
        double d2 = -1e300;
        if (mi >= 0 && mi <= 63 && mj >= 0 && mj <= 63)
            d2 = sqd[192 + lane] + sqd[(oi + 3) * 64 + mj] - 2.0 * dotsd[lane * 50 + oo];
        dotsd[lane * 50 + oo] = d2;
    }
    __syncthreads();
    if (wv == 0) {
        unsigned long long mask = 0ull;
        for (int k = 0; k < 9; ++k) {
            double best = -1e308; int bi = 0;
            for (int oo = 0; oo < 49; ++oo) {
                if ((mask >> oo) & 1ull) continue;
                double vv = dotsd[lane * 50 + oo];
                if (vv > best) { best = vv; bi = oo; }
            }
            mask |= (1ull << bi);
            sels[lane * 9 + k] = bi;
        }
    }
    __syncthreads();
    int rk[9], cj[9];
    #pragma unroll
    for (int k = 0; k < 9; ++k) {
        int oo = sels[lane * 9 + k];
        rk[k] = oo / 7;
        cj[k] = lane + (oo % 7) - 3;
    }
    for (int q = 0; q < 8; ++q) {
        __syncthreads();
        for (int s = t; s < 896; s += 512) {
            int rc = s >> 4, x4 = s & 15;
            int r = rc >> 3, c = rc & 7;
            int gr = i - 3 + r;
            if (gr >= 0 && gr <= 63)
                *(float4*)(tileq + rc * 68 + x4 * 4) =
                    *(const float4*)(catp(o, b * 128 + q * 8 + c) + gr * 64 + x4 * 4);
        }
        __syncthreads();
        {
            int c = wv;
            float s = 0.f;
            #pragma unroll
            for (int k = 0; k < 9; ++k) s += tileq[(rk[k] * 8 + c) * 68 + cj[k]];
            float outv = s * (1.f / 9.f) - tileq[(24 + c) * 68 + lane];
            catp(o, b * 128 + 64 + q * 8 + c)[i * 64 + lane] = outv;
        }
    }
}

// ---------------- K3: 3x3 conv (128->64) + BN + ReLU, LDS-staged weights+inputs
// grid: 256 = B*64 rows; block 1024 (co=lane, jg=t>>6 in 0..15, 4 cols each).
// LDS 49.5KB: wlds[16][9][64] 36KB + xlds[3][16][72] 13.5KB. 8 stages of 16 ci.
__global__ __launch_bounds__(1024) void k3_conv(
    float* __restrict__ o, const float* __restrict__ b1,
    const float* __restrict__ g, const float* __restrict__ be,
    const float* __restrict__ m, const float* __restrict__ v)
{
    __shared__ __align__(16) float wlds[16 * 9 * 64];
    __shared__ __align__(16) float xlds[3 * 16 * 72];
    int blk = blockIdx.x;
    int b = blk >> 6, i = blk & 63;
    int t = threadIdx.x;
    int co = t & 63, jg = t >> 6;
    float acc0 = 0.f, acc1 = 0.f, acc2 = 0.f, acc3 = 0.f;
    const float4 z4 = make_float4(0.f, 0.f, 0.f, 0.f);
    for (int st = 0; st < 8; ++st) {
        __syncthreads();
        // stage weights for ci = st*16 .. st*16+15 : 9216 f32, coalesced
        for (int idx = t; idx < 9216; idx += 1024) {
            int kk = st * 144 + (idx >> 6);
            wlds[idx] = wtv(o, kk, idx & 63);
        }
        // stage inputs: 48 rows (ry,cl) x 18 float4; data col at tile idx +4
        for (int f = t; f < 864; f += 1024) {
            int x4 = f % 18, rc = f / 18;
            int ry = rc >> 4, cl = rc & 15;
            int gr = i - 1 + ry;
            float4 val = z4;
            if (x4 >= 1 && x4 <= 16 && gr >= 0 && gr <= 63)
                val = *(const float4*)(catp(o, b * 128 + st * 16 + cl) + gr * 64 + (x4 - 1) * 4);
            *(float4*)(xlds + rc * 72 + x4 * 4) = val;
        }
        __syncthreads();
        for (int cl = 0; cl < 16; ++cl) {
            #pragma unroll
            for (int ry = 0; ry < 3; ++ry) {
                float w0  = wlds[(cl * 9 + ry * 3 + 0) * 64 + co];
                float w1f = wlds[(cl * 9 + ry * 3 + 1) * 64 + co];
                float w2  = wlds[(cl * 9 + ry * 3 + 2) * 64 + co];
                const float* xr = xlds + (ry * 16 + cl) * 72 + jg * 4;
                float4 q0 = *(const float4*)(xr);
                float4 q1 = *(const float4*)(xr + 4);
                float4 q2 = *(const float4*)(xr + 8);
                float xv[12] = { q0.x,q0.y,q0.z,q0.w, q1.x,q1.y,q1.z,q1.w, q2.x,q2.y,q2.z,q2.w };
                acc0 = fmaf(w0, xv[3], fmaf(w1f, xv[4], fmaf(w2, xv[5], acc0)));
                acc1 = fmaf(w0, xv[4], fmaf(w1f, xv[5], fmaf(w2, xv[6], acc1)));
                acc2 = fmaf(w0, xv[5], fmaf(w1f, xv[6], fmaf(w2, xv[7], acc2)));
                acc3 = fmaf(w0, xv[6], fmaf(w1f, xv[7], fmaf(w2, xv[8], acc3)));
            }
        }
    }
    float sc = g[co] * rsqrtf(v[co] + 1e-5f);
    float sh = b1[co] - m[co];
    float bb = be[co];
    float4 ov;
    ov.x = fmaxf(0.f, fmaf(acc0 + sh, sc, bb));
    ov.y = fmaxf(0.f, fmaf(acc1 + sh, sc, bb));
    ov.z = fmaxf(0.f, fmaf(acc2 + sh, sc, bb));
    ov.w = fmaxf(0.f, fmaf(acc3 + sh, sc, bb));
    *(float4*)(o + (size_t)(b * 64 + co) * 65536 + i * 64 + jg * 4) = ov;
}

// ---------------- K4a: per-plane spatial mean -> slot[12288]
__global__ __launch_bounds__(256) void k4_mean(float* __restrict__ o) {
    int q = blockIdx.x, t = threadIdx.x;
    const float* p = o + (size_t)q * 65536;
    float s = 0.f;
    for (int k = t; k < 4096; k += 256) s += p[k];
    #pragma unroll
    for (int off = 32; off > 0; off >>= 1) s += __shfl_down(s, off, 64);
    __shared__ float red[4];
    if ((t & 63) == 0) red[t >> 6] = s;
    __syncthreads();
    if (t == 0) o[(size_t)q * 65536 + 12288] = (red[0] + red[1] + red[2] + red[3]) * (1.f / 4096.f);
}

// ---------------- K4b: 1x1 conv + BN + sigmoid -> slot[12289]
__global__ __launch_bounds__(256) void k4_att(float* __restrict__ o, const float* __restrict__ wa,
    const float* __restrict__ g, const float* __restrict__ be, const float* __restrict__ m, const float* __restrict__ v) {
    int t = threadIdx.x;
    int b = t >> 6, co = t & 63;
    const float* wr = wa + co * 64;
    float s = 0.f;
    for (int ci = 0; ci < 64; ++ci) s = fmaf(wr[ci], o[(size_t)(b * 64 + ci) * 65536 + 12288], s);
    float sc = g[co] * rsqrtf(v[co] + 1e-5f);
    float y = fmaf(s - m[co], sc, be[co]);
    o[(size_t)t * 65536 + 12289] = 1.f / (1.f + expf(-y));
}

// ---------------- K5: out = bilinear_x4(feat)*att, in place over own slot. block 1024.
__global__ __launch_bounds__(1024) void k5_up(float* __restrict__ o) {
    __shared__ __align__(16) float fplane[4096];
    int bc = blockIdx.x;
    int t = threadIdx.x;
    float* slot = o + (size_t)bc * 65536;
    *(float4*)(fplane + t * 4) = *(const float4*)(slot + t * 4);
    float att = slot[12289];
    __syncthreads();
    int ox = t & 255, oyc = t >> 8;
    float fx = ox * 0.25f - 0.375f;
    int ix = (int)floorf(fx);
    float wx = fx - (float)ix;
    int x0 = ix < 0 ? 0 : ix;
    int x1 = (ix + 1 > 63) ? 63 : ix + 1;
    for (int oy = oyc * 64; oy < oyc * 64 + 64; ++oy) {
        float fy = oy * 0.25f - 0.375f;
        int iy = (int)floorf(fy);
        float wy = fy - (float)iy;
        int y0 = iy < 0 ? 0 : iy;
        int y1 = (iy + 1 > 63) ? 63 : iy + 1;
        float a  = fplane[y0 * 64 + x0], b_ = fplane[y0 * 64 + x1];
        float c_ = fplane[y1 * 64 + x0], d_ = fplane[y1 * 64 + x1];
        float top = a + wx * (b_ - a);
        float bot = c_ + wx * (d_ - c_);
        float val = (top + wy * (bot - top)) * att;
        slot[oy * 256 + ox] = val;
    }
}

extern "C" void kernel_launch(void* const* d_in, const int* in_sizes, int n_in,
                              void* d_out, int out_size, void* d_ws, size_t ws_size,
                              hipStream_t stream) {
    const float* x     = (const float*)d_in[0];
    const float* wd    = (const float*)d_in[1];
    const float* bd    = (const float*)d_in[2];
    const float* bnd_g = (const float*)d_in[3];
    const float* bnd_b = (const float*)d_in[4];
    const float* bnd_m = (const float*)d_in[5];
    const float* bnd_v = (const float*)d_in[6];
    const float* w1    = (const float*)d_in[7];
    const float* b1    = (const float*)d_in[8];
    const float* bn1_g = (const float*)d_in[9];
    const float* bn1_b = (const float*)d_in[10];
    const float* bn1_m = (const float*)d_in[11];
    const float* bn1_v = (const float*)d_in[12];
    const float* wa    = (const float*)d_in[13];
    const float* bna_g = (const float*)d_in[14];
    const float* bna_b = (const float*)d_in[15];
    const float* bna_m = (const float*)d_in[16];
    const float* bna_v = (const float*)d_in[17];

    float* o = (float*)d_out;

    hipLaunchKernelGGL(k0_wtrans, dim3(288), dim3(256), 0, stream, w1, o);
    hipLaunchKernelGGL(k1_convds, dim3(512), dim3(256), 0, stream,
                       x, wd, bd, bnd_g, bnd_b, bnd_m, bnd_v, o);
    hipLaunchKernelGGL(k2_feat, dim3(256), dim3(512), 0, stream, o);
    hipLaunchKernelGGL(k3_conv, dim3(256), dim3(1024), 0, stream,
                       o, b1, bn1_g, bn1_b, bn1_m, bn1_v);
    hipLaunchKernelGGL(k4_mean, dim3(256), dim3(256), 0, stream, o);
    hipLaunchKernelGGL(k4_att, dim3(1), dim3(256), 0, stream,
                       o, wa, bna_g, bna_b, bna_m, bna_v);
    hipLaunchKernelGGL(k5_up, dim3(256), dim3(1024), 0, stream, o);
}